// Round 10
// baseline (237.674 us; speedup 1.0000x reference)
//
#include <hip/hip_runtime.h>

// NCN recurrence, 2 layers fused into ONE persistent kernel.
// B=4, N=4096, E=128, NK=4, ce=32, CACHE=32, m=128.
// 2048 independent [32 rows x 32 feats] subproblems per layer; one WAVE per
// subproblem. Grid = 256 blocks x 512 threads (8 waves/block, 1 block/CU
// guaranteed co-resident: 2048 waves << 8192 slots) so a device-scope
// atomic grid barrier between layers is deadlock-free (256 arrivals ~2us).
// Layer 0: d_in -> ws(mid); grid barrier (+threadfence both sides for
// cross-XCD visibility); layer 1: ws(mid) -> d_out. Barrier counters live in
// ws[0..511], zeroed by hipMemsetAsync each launch -> replay/idempotent-safe.
//
// Per-wave scan step (wave-contained, no block barrier):
//   - 16x ds_bpermute pulls row j's 16-feat slice from lane (h*32+j)
//     (no LDS storage, register use-def ordering, cross-step pipelining);
//   - u = dot16(xi,wi) + dot16(xj,wj); sim = u + shfl_xor(u,32)  -- ONE
//     cross-lane op (xj identical across lanes of a half => Wj term uniform);
//   - weights pre-scaled by L1=log2(e); tanh via 0.1F = 0.1 - 0.2/(exp2+1),
//     arg = L1*xi + (L1*sim)*xj, unclamped (over/underflow -> exact +-1).

namespace {
constexpr int kB = 4;
constexpr int kN = 4096;
constexpr int kE = 128;
constexpr int kCE = 32;          // E / NK
constexpr int kH  = 16;          // feats per lane
constexpr int kQ  = kH / 2;      // float2 count
constexpr int kCache = 32;
constexpr int kM = kN / kCache;  // 128 groups per batch
constexpr int kBlocks = 256;
constexpr int kThreads = 512;    // 8 waves/block

typedef __attribute__((ext_vector_type(2))) float f32x2;

__device__ __forceinline__ f32x2 pk_fma(f32x2 a, f32x2 b, f32x2 c) {
    return __builtin_elementwise_fma(a, b, c);
}
}  // namespace

__device__ __forceinline__ void load_state(
    const float* __restrict__ xp, const float* __restrict__ ap,
    f32x2* xi, f32x2* xa)
{
    const float4* x4 = reinterpret_cast<const float4*>(xp);
    const float4* a4 = reinterpret_cast<const float4*>(ap);
#pragma unroll
    for (int q = 0; q < kQ / 2; ++q) {
        float4 v = x4[q];
        xi[2 * q + 0] = f32x2{v.x, v.y}; xi[2 * q + 1] = f32x2{v.z, v.w};
        float4 a = a4[q];
        xa[2 * q + 0] = f32x2{a.x, a.y}; xa[2 * q + 1] = f32x2{a.z, a.w};
    }
}

__device__ __forceinline__ void store_state(
    float* __restrict__ xp, float* __restrict__ ap,
    const f32x2* xi, const f32x2* xa)
{
    float4* x4 = reinterpret_cast<float4*>(xp);
    float4* a4 = reinterpret_cast<float4*>(ap);
#pragma unroll
    for (int q = 0; q < kQ / 2; ++q) {
        float4 v;
        v.x = xi[2 * q + 0].x; v.y = xi[2 * q + 0].y;
        v.z = xi[2 * q + 1].x; v.w = xi[2 * q + 1].y;
        x4[q] = v;
        float4 a;
        a.x = xa[2 * q + 0].x; a.y = xa[2 * q + 0].y;
        a.z = xa[2 * q + 1].x; a.w = xa[2 * q + 1].y;
        a4[q] = a;
    }
}

// One layer's scan for this wave's subproblem; xi/xa updated in place.
__device__ __forceinline__ void scan_layer(
    f32x2* xi, f32x2* xa,
    const f32x2* wi, const f32x2* wj,   // pre-scaled by L1
    int lane)
{
    constexpr float L1 = 1.4426950408889634f;
    const int srcbase = (lane & 32) * 4;   // xj source lane = (lane&32) + j

#pragma unroll 2
    for (int j = 0; j < kCache; ++j) {
        const int srcaddr = srcbase + j * 4;

        // (1) pull row j's slice: 16 independent bpermutes
        f32x2 xj[kQ];
#pragma unroll
        for (int q = 0; q < kQ; ++q) {
            xj[q].x = __int_as_float(
                __builtin_amdgcn_ds_bpermute(srcaddr, __float_as_int(xi[q].x)));
            xj[q].y = __int_as_float(
                __builtin_amdgcn_ds_bpermute(srcaddr, __float_as_int(xi[q].y)));
        }

        // (2) u = dot16(xi,wi) + dot16(xj,wj)
        f32x2 a01 = xi[0] * wi[0];
        f32x2 a23 = xi[1] * wi[1];
        f32x2 b01 = xj[0] * wj[0];
        f32x2 b23 = xj[1] * wj[1];
#pragma unroll
        for (int q = 2; q < kQ; q += 2) {
            a01 = pk_fma(xi[q + 0], wi[q + 0], a01);
            a23 = pk_fma(xi[q + 1], wi[q + 1], a23);
            b01 = pk_fma(xj[q + 0], wj[q + 0], b01);
            b23 = pk_fma(xj[q + 1], wj[q + 1], b23);
        }
        f32x2 uv = (a01 + a23) + (b01 + b23);
        float u  = uv.x + uv.y;

        // (3) one cross-lane op: combine the two 16-feat halves
        const float sim = u + __shfl_xor(u, 32, 64);   // = L1 * sim_true
        const f32x2 sv  = {sim, sim};
        const f32x2 l12 = {L1, L1};
        const f32x2 one = {1.0f, 1.0f};
        const f32x2 m02 = {-0.2f, -0.2f};
        const f32x2 c9  = {0.9f, 0.9f};
        const f32x2 c01 = {0.1f, 0.1f};

#pragma unroll
        for (int q = 0; q < kQ; ++q) {
            f32x2 arg = pk_fma(xj[q], sv, xi[q] * l12);  // 2*L1*T
            f32x2 t2;
            t2.x = __builtin_amdgcn_exp2f(arg.x);
            t2.y = __builtin_amdgcn_exp2f(arg.y);
            f32x2 den = t2 + one;
            f32x2 rc;
            rc.x = __builtin_amdgcn_rcpf(den.x);
            rc.y = __builtin_amdgcn_rcpf(den.y);
            xa[q] = pk_fma(m02, rc, pk_fma(c9, xa[q], c01));  // 0.9xa+0.1F
            xi[q] = pk_fma(c01, xa[q], xi[q] * c9);           // 0.9xi+0.1ya
        }
    }
}

__global__ void __launch_bounds__(kThreads, 1) ncn_fused_kernel(
    const float* __restrict__ x_in, const float* __restrict__ xa_in,
    const float* __restrict__ W,    // 2 layers x 256 floats
    float* __restrict__ x_mid, float* __restrict__ xa_mid,
    float* __restrict__ x_out, float* __restrict__ xa_out,
    unsigned* __restrict__ bar_cnt, unsigned* __restrict__ bar_gen)
{
    const int tid  = threadIdx.x;
    const int wave = tid >> 6;
    const int lane = tid & 63;
    const int id   = blockIdx.x * 8 + wave;   // subproblem id, 0..2047
    const int n    = id & 3;
    const int g    = (id >> 2) & (kM - 1);
    const int b    = id >> 9;
    const int o    = lane & 31;
    const int h    = lane >> 5;

    constexpr float L1 = 1.4426950408889634f;

    // ---- layer 0 (s = 0): row = g*32 + o ----
    const int r0 = (g << 5) + o;
    const size_t base0 = ((size_t)(b * kN + r0)) * kE + n * kCE + h * kH;

    f32x2 xi[kQ], xa[kQ], wi[kQ], wj[kQ];
    load_state(x_in + base0, xa_in + base0, xi, xa);
    {
        const float4* wi4 = reinterpret_cast<const float4*>(W + n * kCE + h * kH);
        const float4* wj4 = reinterpret_cast<const float4*>(W + kE + n * kCE + h * kH);
#pragma unroll
        for (int q = 0; q < kQ / 2; ++q) {
            float4 u = wi4[q];
            wi[2 * q + 0] = f32x2{u.x * L1, u.y * L1};
            wi[2 * q + 1] = f32x2{u.z * L1, u.w * L1};
            float4 w = wj4[q];
            wj[2 * q + 0] = f32x2{w.x * L1, w.y * L1};
            wj[2 * q + 1] = f32x2{w.z * L1, w.w * L1};
        }
    }

    scan_layer(xi, xa, wi, wj, lane);
    store_state(x_mid + base0, xa_mid + base0, xi, xa);

    // ---- grid barrier (256 block-arrivals, device scope) ----
    __threadfence();          // make mid stores visible device-wide
    __syncthreads();          // all waves of this block done
    if (tid == 0) {
        unsigned arrived = __hip_atomic_fetch_add(
            bar_cnt, 1u, __ATOMIC_ACQ_REL, __HIP_MEMORY_SCOPE_AGENT) + 1;
        if (arrived == (unsigned)kBlocks) {
            __hip_atomic_store(bar_gen, 1u, __ATOMIC_RELEASE,
                               __HIP_MEMORY_SCOPE_AGENT);
        } else {
            while (__hip_atomic_load(bar_gen, __ATOMIC_ACQUIRE,
                                     __HIP_MEMORY_SCOPE_AGENT) == 0u) {
                __builtin_amdgcn_s_sleep(2);
            }
        }
    }
    __syncthreads();
    __threadfence();          // acquire side: see other blocks' mid stores

    // ---- layer 1 (s = 1): row = ((g + o) % m)*32 + o ----
    const int r1 = (((g + o) & (kM - 1)) << 5) + o;
    const size_t base1 = ((size_t)(b * kN + r1)) * kE + n * kCE + h * kH;

    load_state(x_mid + base1, xa_mid + base1, xi, xa);
    {
        const float4* wi4 = reinterpret_cast<const float4*>(W + 2 * kE + n * kCE + h * kH);
        const float4* wj4 = reinterpret_cast<const float4*>(W + 3 * kE + n * kCE + h * kH);
#pragma unroll
        for (int q = 0; q < kQ / 2; ++q) {
            float4 u = wi4[q];
            wi[2 * q + 0] = f32x2{u.x * L1, u.y * L1};
            wi[2 * q + 1] = f32x2{u.z * L1, u.w * L1};
            float4 w = wj4[q];
            wj[2 * q + 0] = f32x2{w.x * L1, w.y * L1};
            wj[2 * q + 1] = f32x2{w.z * L1, w.w * L1};
        }
    }

    scan_layer(xi, xa, wi, wj, lane);
    store_state(x_out + base1, xa_out + base1, xi, xa);
}

extern "C" void kernel_launch(void* const* d_in, const int* in_sizes, int n_in,
                              void* d_out, int out_size, void* d_ws, size_t ws_size,
                              hipStream_t stream) {
    const float* x  = (const float*)d_in[0];   // [B, N, E] fp32
    const float* xa = (const float*)d_in[1];   // [B, N, E] fp32
    const float* W  = (const float*)d_in[2];   // [2, 256] fp32

    const size_t plane = (size_t)kB * kN * kE;   // 2,097,152 floats

    // ws layout: [0..511] barrier state; mid buffers from offset 1024 B.
    unsigned* bar_cnt = (unsigned*)d_ws;               // ws[0]
    unsigned* bar_gen = (unsigned*)((char*)d_ws + 256);
    float* x_mid  = (float*)((char*)d_ws + 1024);
    float* xa_mid = x_mid + plane;

    float* x_out  = (float*)d_out;
    float* xa_out = x_out + plane;

    // zero barrier state (capture-legal async memset; makes launch idempotent)
    hipMemsetAsync(d_ws, 0, 512, stream);

    ncn_fused_kernel<<<dim3(kBlocks), dim3(kThreads), 0, stream>>>(
        x, xa, W, x_mid, xa_mid, x_out, xa_out, bar_cnt, bar_gen);
}

// Round 12
// 121.898 us; speedup vs baseline: 1.9498x; 1.9498x over previous
//
#include <hip/hip_runtime.h>

// NCN recurrence, 2 layers. B=4, N=4096, E=128, NK=4, ce=32, CACHE=32, m=128.
// 2048 independent [32 x 32] subproblems; one single-wave block each.
// Lane (h,o) owns feats [h*16,h*16+16) of row o.
//
// R12 = R11 with the macro-pasting fix (`src##0 .x` -- `0.x` lexes as one
// pp-number, so `src##0.x` formed the invalid token `xi0.x`).
//
// REGISTER FIX theory (from R10 counters): VGPR_Count=52 with >=64 f32 of
// live scan state -> local arrays lived in SCRATCH; every scan step
// round-tripped state through scratch (VALUBusy 15%, WRITE_SIZE +15MB over
// ideal). That unmodeled cost explains why barrier/DS/occupancy restructures
// (R3-R9) were all ~neutral. Fix:
//   - ALL state in named f32x2 variables (xi0..7, xa0..7, wi0..7, wj0..7,
//     xj0..7) -- no local arrays, nothing address-taken -> guaranteed
//     mem2reg. Step body via macros.
//   - __attribute__((amdgpu_waves_per_eu(2,2))): VGPR cap 256, allocator
//     targets exactly the 2 waves/SIMD the grid supplies -> no spills.
// Scan step: 16 bpermute xj pulls (no LDS, no barrier); u = dot16(xi,wi) +
// dot16(xj,wj); sim = u + shfl_xor(u,32) (xj uniform per half => Wj term
// uniform). Weights pre-scaled by L1=log2(e);
// tanh via 0.1F = 0.1 - 0.2/(exp2(arg)+1), arg = L1*xi + (L1*sim)*xj,
// unclamped (exp2 over/underflow -> exact +-1).
// Layer 0: d_in -> d_ws; layer 1: d_ws -> d_out (pure, replay-safe).

namespace {
constexpr int kB = 4;
constexpr int kN = 4096;
constexpr int kE = 128;
constexpr int kCE = 32;          // E / NK
constexpr int kH  = 16;          // feats per lane
constexpr int kCache = 32;
constexpr int kM = kN / kCache;  // 128 groups per batch

typedef __attribute__((ext_vector_type(2))) float f32x2;

__device__ __forceinline__ f32x2 pk_fma(f32x2 a, f32x2 b, f32x2 c) {
    return __builtin_elementwise_fma(a, b, c);
}
__device__ __forceinline__ float bperm_f(int addr, float v) {
    return __int_as_float(__builtin_amdgcn_ds_bpermute(addr, __float_as_int(v)));
}
}  // namespace

// load 16 floats (4x float4) into 8 named f32x2
#define LD16(dst, ptr)                                                  \
    {                                                                   \
        const float4* p4 = reinterpret_cast<const float4*>(ptr);        \
        float4 q0 = p4[0], q1 = p4[1], q2 = p4[2], q3 = p4[3];          \
        dst##0 = f32x2{q0.x, q0.y}; dst##1 = f32x2{q0.z, q0.w};         \
        dst##2 = f32x2{q1.x, q1.y}; dst##3 = f32x2{q1.z, q1.w};         \
        dst##4 = f32x2{q2.x, q2.y}; dst##5 = f32x2{q2.z, q2.w};         \
        dst##6 = f32x2{q3.x, q3.y}; dst##7 = f32x2{q3.z, q3.w};         \
    }

// store 8 named f32x2 as 4x float4 (note: space between digit and `.`!)
#define ST16(src, ptr)                                                  \
    {                                                                   \
        float4* p4 = reinterpret_cast<float4*>(ptr);                    \
        p4[0] = float4{src##0 .x, src##0 .y, src##1 .x, src##1 .y};     \
        p4[1] = float4{src##2 .x, src##2 .y, src##3 .x, src##3 .y};     \
        p4[2] = float4{src##4 .x, src##4 .y, src##5 .x, src##5 .y};     \
        p4[3] = float4{src##6 .x, src##6 .y, src##7 .x, src##7 .y};     \
    }

#define PULL(q)                                                         \
    f32x2 xj##q;                                                        \
    xj##q .x = bperm_f(srcaddr, xi##q .x);                              \
    xj##q .y = bperm_f(srcaddr, xi##q .y);

#define UPD(q)                                                          \
    {                                                                   \
        f32x2 arg = pk_fma(xj##q, sv, xi##q * l12);                     \
        f32x2 t2;                                                       \
        t2.x = __builtin_amdgcn_exp2f(arg.x);                           \
        t2.y = __builtin_amdgcn_exp2f(arg.y);                           \
        f32x2 den = t2 + one;                                           \
        f32x2 rc;                                                       \
        rc.x = __builtin_amdgcn_rcpf(den.x);                            \
        rc.y = __builtin_amdgcn_rcpf(den.y);                            \
        xa##q = pk_fma(m02, rc, pk_fma(c9, xa##q, c01));                \
        xi##q = pk_fma(c01, xa##q, xi##q * c9);                         \
    }

__global__ void __launch_bounds__(64)
__attribute__((amdgpu_waves_per_eu(2, 2)))
ncn_layer_kernel(
    const float* __restrict__ x_in, const float* __restrict__ xa_in,
    const float* __restrict__ Wl,   // this layer's 256 floats
    float* __restrict__ x_out, float* __restrict__ xa_out,
    int s)                          // group stride: 0 for stage 0, 1 for stage 1
{
    const int blk = blockIdx.x;         // ((b*128 + g)*4 + n)
    const int n   = blk & 3;
    const int g   = (blk >> 2) & (kM - 1);
    const int b   = blk >> 9;
    const int t   = threadIdx.x;        // 0..63
    const int o   = t & 31;
    const int h   = t >> 5;

    // row index: ((g + o*s) % m) * CACHE + o
    const int r = (((g + o * s) & (kM - 1)) << 5) + o;
    const size_t base = ((size_t)(b * kN + r)) * kE + n * kCE + h * kH;

    constexpr float L1 = 1.4426950408889634f;   // log2(e)

    f32x2 xi0, xi1, xi2, xi3, xi4, xi5, xi6, xi7;
    f32x2 xa0, xa1, xa2, xa3, xa4, xa5, xa6, xa7;
    f32x2 wi0, wi1, wi2, wi3, wi4, wi5, wi6, wi7;
    f32x2 wj0, wj1, wj2, wj3, wj4, wj5, wj6, wj7;

    LD16(xi, x_in + base);
    LD16(xa, xa_in + base);
    LD16(wi, Wl + n * kCE + h * kH);
    LD16(wj, Wl + kE + n * kCE + h * kH);

    // pre-scale weights by L1: dots yield L1*sim directly
    {
        const f32x2 l12 = {L1, L1};
        wi0 *= l12; wi1 *= l12; wi2 *= l12; wi3 *= l12;
        wi4 *= l12; wi5 *= l12; wi6 *= l12; wi7 *= l12;
        wj0 *= l12; wj1 *= l12; wj2 *= l12; wj3 *= l12;
        wj4 *= l12; wj5 *= l12; wj6 *= l12; wj7 *= l12;
    }

    // bpermute byte-address base: xj source lane = (t & 32) + j
    const int srcbase = (t & 32) * 4;

#pragma unroll 2
    for (int j = 0; j < kCache; ++j) {
        const int srcaddr = srcbase + j * 4;

        // (1) pull row j's slice: 16 independent bpermutes
        PULL(0) PULL(1) PULL(2) PULL(3) PULL(4) PULL(5) PULL(6) PULL(7)

        // (2) u = dot16(xi,wi) + dot16(xj,wj); 4 packed accumulators
        f32x2 A = xi0 * wi0;
        f32x2 B = xi1 * wi1;
        f32x2 C = xj0 * wj0;
        f32x2 D = xj1 * wj1;
        A = pk_fma(xi2, wi2, A); B = pk_fma(xi3, wi3, B);
        C = pk_fma(xj2, wj2, C); D = pk_fma(xj3, wj3, D);
        A = pk_fma(xi4, wi4, A); B = pk_fma(xi5, wi5, B);
        C = pk_fma(xj4, wj4, C); D = pk_fma(xj5, wj5, D);
        A = pk_fma(xi6, wi6, A); B = pk_fma(xi7, wi7, B);
        C = pk_fma(xj6, wj6, C); D = pk_fma(xj7, wj7, D);
        f32x2 uv = (A + B) + (C + D);
        float u  = uv.x + uv.y;

        // (3) one cross-lane op: combine the two 16-feat halves
        const float sim = u + __shfl_xor(u, 32, 64);   // = L1 * sim_true
        const f32x2 sv  = {sim, sim};
        const f32x2 l12 = {L1, L1};
        const f32x2 one = {1.0f, 1.0f};
        const f32x2 m02 = {-0.2f, -0.2f};
        const f32x2 c9  = {0.9f, 0.9f};
        const f32x2 c01 = {0.1f, 0.1f};

        UPD(0) UPD(1) UPD(2) UPD(3) UPD(4) UPD(5) UPD(6) UPD(7)
    }

    ST16(xi, x_out + base);
    ST16(xa, xa_out + base);
}

extern "C" void kernel_launch(void* const* d_in, const int* in_sizes, int n_in,
                              void* d_out, int out_size, void* d_ws, size_t ws_size,
                              hipStream_t stream) {
    const float* x  = (const float*)d_in[0];   // [B, N, E] fp32
    const float* xa = (const float*)d_in[1];   // [B, N, E] fp32
    const float* W  = (const float*)d_in[2];   // [2, 256] fp32

    const size_t plane = (size_t)kB * kN * kE;   // 2,097,152 floats

    float* x_mid  = (float*)d_ws;                // layer-0 outputs in workspace
    float* xa_mid = x_mid + plane;               // (32 MB total)

    float* x_out  = (float*)d_out;               // final outputs
    float* xa_out = x_out + plane;

    const dim3 grid(kB * kM * 4);   // 2048 single-wave blocks
    const dim3 block(64);

    // Layer 0 (stage 0, s = 0): d_in -> ws       (pure, idempotent)
    ncn_layer_kernel<<<grid, block, 0, stream>>>(x, xa, W, x_mid, xa_mid, 0);
    // Layer 1 (stage 1, s = 1): ws -> d_out      (pure, idempotent)
    ncn_layer_kernel<<<grid, block, 0, stream>>>(x_mid, xa_mid, W + 2 * kE,
                                                 x_out, xa_out, 1);
}